// Round 9
// baseline (349.757 us; speedup 1.0000x reference)
//
#include <hip/hip_runtime.h>

typedef unsigned short ushort_t;
typedef __attribute__((ext_vector_type(8))) short short8;
typedef __attribute__((ext_vector_type(4))) float f32x4;
typedef __attribute__((ext_vector_type(2))) float f32x2;
typedef __attribute__((ext_vector_type(4))) int int4v;

#define RNUM 8
#define FDIM 128

__device__ __forceinline__ float bf2f(ushort_t u) {
    union { unsigned int i; float f; } x;
    x.i = ((unsigned int)u) << 16;
    return x.f;
}
__device__ __forceinline__ float asf(unsigned int u) {
    union { unsigned int i; float f; } x;
    x.i = u;
    return x.f;
}
__device__ __forceinline__ ushort_t f2bf(float f) {
    union { float f; unsigned int i; } x;
    x.f = f;
    unsigned int u = x.i;
    u += 0x7fffu + ((u >> 16) & 1u);   // round-to-nearest-even
    return (ushort_t)(u >> 16);
}

// ---------------- multi-head linked-list segment index ----------------
// 4 BALANCED sub-lists per segment: edge with per-segment arrival rank q goes
// to sub-chain q&3 (round-robin via atomicAdd on cnt[seg]). Balanced chains
// cut seg_mean loop iterations from E[max multinomial(d,4)] (~1.45) to
// ceil(d/4) (~1.05). cnt[seg] doubles as the mean divisor (precomputed).
// meta[i] = (src[i], prev edge in same (seg,k) list). One 8B load per hop.

__global__ void init_head(int* __restrict__ head, int* __restrict__ cnt, int nseg) {
    int i = blockIdx.x * 256 + threadIdx.x;
    if (i < nseg * 4) head[i] = -1;
    if (i < nseg) cnt[i] = 0;
}

__global__ void link_kernel(const int* __restrict__ src, const int* __restrict__ dst,
                            const int* __restrict__ et,
                            int* head, int* cnt, int2* __restrict__ meta, int E) {
    int i = blockIdx.x * 256 + threadIdx.x;
    if (i < E) {
        int seg = dst[i] * RNUM + et[i];
        int rank = atomicAdd(&cnt[seg], 1);
        int prev = atomicExch(&head[seg * 4 + (rank & 3)], i);
        meta[i] = make_int2(src[i], prev);
    }
}

// ------- weight transpose + bf16 cast: Wt[l][r][h][f] = bf16(W_l[r][f][h]), r=8 -> root ----
// both layers in one launch (18 blocks)

__global__ __launch_bounds__(256) void transpose_w(const float* __restrict__ rel_w0,
                                                   const float* __restrict__ root_w0,
                                                   const float* __restrict__ rel_w1,
                                                   const float* __restrict__ root_w1,
                                                   ushort_t* __restrict__ Wt) {
    int b = blockIdx.x;            // 0..17
    int layer = (b >= 9) ? 1 : 0;
    int r = b - layer * 9;         // 0..8
    const float* rel  = layer ? rel_w1 : rel_w0;
    const float* root = layer ? root_w1 : root_w0;
    const float* src = (r < 8) ? (rel + r * 16384) : root;
    __shared__ ushort_t t[128 * 130];
    for (int idx = threadIdx.x; idx < 16384; idx += 256)
        t[(idx >> 7) * 130 + (idx & 127)] = f2bf(src[idx]);
    __syncthreads();
    ushort_t* d = Wt + (layer * 9 + r) * 16384;
    for (int idx = threadIdx.x; idx < 16384; idx += 256)
        d[idx] = t[(idx & 127) * 130 + (idx >> 7)];
}

// ---------------- cast x (f32) into compact bf16 buffer; pad rows zeroed ----------------

__global__ void cast_x(const float* __restrict__ x, ushort_t* __restrict__ xc,
                       int total, int totalPad) {
    int i = (blockIdx.x * 256 + threadIdx.x) * 8;
    if (i >= totalPad) return;
    ushort_t o[8];
    if (i < total) {
        float4 v0 = *(const float4*)(x + i);
        float4 v1 = *(const float4*)(x + i + 4);
        o[0] = f2bf(v0.x); o[1] = f2bf(v0.y); o[2] = f2bf(v0.z); o[3] = f2bf(v0.w);
        o[4] = f2bf(v1.x); o[5] = f2bf(v1.y); o[6] = f2bf(v1.z); o[7] = f2bf(v1.w);
    } else {
#pragma unroll
        for (int k = 0; k < 8; ++k) o[k] = 0;
    }
    *(int4v*)(xc + i) = *(int4v*)o;
}

// ---------------- phase A: per-(node,rel) segment means ----------------
// One quarter-wave (16 lanes x 16B) per segment; the segment's 4 balanced
// sub-chains walked interleaved (4 independent gathers in flight).
// Exec-masked guards: dead chains issue no loads. pow2 addressing.
// Accumulate in f32 PAIRS (u<<16 / u&0xffff0000 unpack + v_pk_add_f32):
// 3 VALU per 2 elems. Count tracking removed (cnt precomputed by linker).

__global__ __launch_bounds__(256) void seg_mean(const int4v* __restrict__ head4,
                                                const int2* __restrict__ meta,
                                                const int* __restrict__ cntArr,
                                                const ushort_t* __restrict__ X,   // [NPAD][128]
                                                ushort_t* __restrict__ Mm,        // [NPAD][8][128]
                                                int NSEG) {
    int t = blockIdx.x * 256 + threadIdx.x;
    int seg = t >> 4;
    int l16 = t & 15;
    if (seg >= NSEG) return;
    const ushort_t* gbase = X + l16 * 8;

    int cnt = cntArr[seg];           // issued early; uniform across the qw
    int4v h4 = head4[seg];           // 4 sub-chain heads in one 16B load

    f32x2 acc[4];
#pragma unroll
    for (int k = 0; k < 4; ++k) acc[k] = (f32x2){0.f, 0.f};

    int j[4], s[4], n[4];
#pragma unroll
    for (int c = 0; c < 4; ++c) j[c] = h4[c];
#pragma unroll
    for (int c = 0; c < 4; ++c)
        if (j[c] >= 0) { int2 m = meta[j[c]]; s[c] = m.x; n[c] = m.y; }

    // loop while ANY sub-chain active (AND of ids has sign bit set iff all -1)
    while ((j[0] & j[1] & j[2] & j[3]) >= 0) {
        int4v v[4];
#pragma unroll
        for (int c = 0; c < 4; ++c)
            if (j[c] >= 0) v[c] = *(const int4v*)(gbase + ((size_t)s[c] << 7));
        int2 m2[4];
#pragma unroll
        for (int c = 0; c < 4; ++c)
            if (j[c] >= 0 && n[c] >= 0) m2[c] = meta[n[c]];
#pragma unroll
        for (int c = 0; c < 4; ++c) {
            if (j[c] >= 0) {
#pragma unroll
                for (int kp = 0; kp < 4; ++kp) {
                    unsigned int u = (unsigned int)v[c][kp];
                    acc[kp] += (f32x2){asf(u << 16), asf(u & 0xffff0000u)};
                }
                j[c] = n[c];
                s[c] = m2[c].x;
                n[c] = m2[c].y;
            }
        }
    }

    float sc = (cnt > 0) ? 1.0f / (float)cnt : 0.f;
    ushort_t ov[8];
#pragma unroll
    for (int kp = 0; kp < 4; ++kp) {
        ov[2 * kp]     = f2bf(acc[kp].x * sc);
        ov[2 * kp + 1] = f2bf(acc[kp].y * sc);
    }
    *(int4v*)(Mm + ((size_t)seg << 7) + l16 * 8) = *(int4v*)ov;
}

// ---------------- phase B: dense GEMM  C[128n x 128h] = [Mm | Xc] @ Wt^T ----------------
// Register-staged K-slot pipeline (slot r+1's chunks in flight during slot
// r's MFMAs; ds_write after the post-compute barrier). 512 threads / 8 waves
// per block -> 16 waves/CU at 2 blocks/CU, so one wave's staging vmcnt stall
// is covered by other waves' MFMAs.

template <bool FINAL>
__global__ __launch_bounds__(512, 4) void rgcn_gemm(
    const ushort_t* __restrict__ Mm,   // [NPAD][8*128]
    const ushort_t* __restrict__ Xc,   // [NPAD][128]  (slot 8 / root input)
    const ushort_t* __restrict__ Wt,   // [9][128][128]
    const float* __restrict__ bias, float* __restrict__ outF,
    ushort_t* __restrict__ Xout, int N) {
    __shared__ ushort_t As[128 * 128];
    __shared__ ushort_t Bs[128 * 128];
    int tid = threadIdx.x;
    int wv = tid >> 6, lane = tid & 63;
    int l16 = lane & 15, q = lane >> 4;
    int nodeBase = blockIdx.x * 128;

    f32x4 acc[8];
#pragma unroll
    for (int ct = 0; ct < 8; ++ct) acc[ct] = (f32x4){0.f, 0.f, 0.f, 0.f};

    int4v aReg[4], bReg[4];

    auto issueLoads = [&](int r) {
#pragma unroll
        for (int i = 0; i < 4; ++i) {
            int L = i * 512 + tid;          // 16B slot index, wave-contiguous
            int row = L >> 4;               // 0..127
            int c = (L & 15) ^ (row & 15);  // logical chunk for this slot (swizzle)
            const ushort_t* ga = (r < 8)
                ? Mm + ((size_t)(nodeBase + row) << 10) + r * 128 + c * 8
                : Xc + ((size_t)(nodeBase + row) << 7) + c * 8;
            aReg[i] = *(const int4v*)ga;
            bReg[i] = *(const int4v*)(Wt + r * 16384 + row * 128 + c * 8);
        }
    };
    auto writeLds = [&]() {
#pragma unroll
        for (int i = 0; i < 4; ++i) {
            int L = i * 512 + tid;
            *(int4v*)((char*)As + (size_t)L * 16) = aReg[i];
            *(int4v*)((char*)Bs + (size_t)L * 16) = bReg[i];
        }
    };

    issueLoads(0);
    writeLds();
    __syncthreads();

    for (int r = 0; r < 9; ++r) {
        if (r < 8) issueLoads(r + 1);       // in flight across the compute phase
#pragma unroll
        for (int s = 0; s < 4; ++s) {
            int pos = ((s * 4 + q) ^ l16) * 16;
            short8 a = *(const short8*)((const char*)As + (wv * 16 + l16) * 256 + pos);
#pragma unroll
            for (int ct = 0; ct < 8; ++ct) {
                short8 b = *(const short8*)((const char*)Bs + (ct * 16 + l16) * 256 + pos);
                acc[ct] = __builtin_amdgcn_mfma_f32_16x16x32_bf16(a, b, acc[ct], 0, 0, 0);
            }
        }
        __syncthreads();                     // all LDS reads of slot r done
        if (r < 8) {
            writeLds();                      // waits vmcnt on the staged regs only
            __syncthreads();                 // writes visible before next compute
        }
    }

    // epilogue: C layout col = lane&15, row = q*4 + reg (within wave's 16-row tile)
#pragma unroll
    for (int ct = 0; ct < 8; ++ct) {
        int h = ct * 16 + l16;
        float bv = bias[h];
#pragma unroll
        for (int reg = 0; reg < 4; ++reg) {
            int node = nodeBase + wv * 16 + q * 4 + reg;
            float v = acc[ct][reg] + bv;
            if (FINAL) {
                if (node < N) outF[(size_t)node * FDIM + h] = v;
            } else {
                // pad rows written as 0 (keeps h1c defined; acc there is garbage)
                Xout[(size_t)node * FDIM + h] =
                    (node < N) ? f2bf(fmaxf(v, 0.f)) : (ushort_t)0;
            }
        }
    }
}

__global__ void copy_emb(const float* __restrict__ e, float* __restrict__ out, int n) {
    int i = blockIdx.x * 256 + threadIdx.x;
    if (i < n) out[i] = e[i];
}

// ---------------- launch ----------------

extern "C" void kernel_launch(void* const* d_in, const int* in_sizes, int n_in,
                              void* d_out, int out_size, void* d_ws, size_t ws_size,
                              hipStream_t stream) {
    const float* x        = (const float*)d_in[0];
    const int* edge_index = (const int*)d_in[1];
    const int* edge_type  = (const int*)d_in[2];
    const float* rel_w0   = (const float*)d_in[3];
    const float* root_w0  = (const float*)d_in[4];
    const float* bias0    = (const float*)d_in[5];
    const float* rel_w1   = (const float*)d_in[6];
    const float* root_w1  = (const float*)d_in[7];
    const float* bias1    = (const float*)d_in[8];
    const float* rel_emb  = (const float*)d_in[9];

    int N = in_sizes[0] / FDIM;   // 50000
    int E = in_sizes[1] / 2;      // 800000
    int NSEG = N * RNUM;          // 400000
    const int* src = edge_index;
    const int* dst = edge_index + E;

    int nb_gemm = (N + 127) / 128;      // 391
    int NPAD = nb_gemm * 128;           // 50048

    char* w = (char*)d_ws;
    auto alloc = [&](size_t bytes) -> char* {
        char* p = w;
        w += (bytes + 255) & ~(size_t)255;
        return p;
    };
    int* head     = (int*)alloc((size_t)NSEG * 4 * 4);          // 4 sub-lists per segment
    int* cnt      = (int*)alloc((size_t)NSEG * 4);              // per-seg edge count
    int2* meta    = (int2*)alloc((size_t)E * 8);
    ushort_t* Wt  = (ushort_t*)alloc((size_t)2 * 9 * 16384 * 2);
    ushort_t* xc  = (ushort_t*)alloc((size_t)NPAD * FDIM * 2);        // 12.8 MB
    ushort_t* h1c = (ushort_t*)alloc((size_t)NPAD * FDIM * 2);        // 12.8 MB
    ushort_t* Mm  = (ushort_t*)alloc((size_t)NPAD * RNUM * FDIM * 2); // ~102.5 MB
    (void)ws_size; (void)n_in; (void)out_size;

    int nb_head = (NSEG * 4 + 255) / 256;
    int nb_E    = (E + 255) / 256;
    int nb_mean = (NSEG * 16) / 256;                 // 25000
    int nb_cast = (NPAD * FDIM) / (256 * 8);         // 3128

    init_head<<<nb_head, 256, 0, stream>>>(head, cnt, NSEG);
    link_kernel<<<nb_E, 256, 0, stream>>>(src, dst, edge_type, head, cnt, meta, E);
    transpose_w<<<18, 256, 0, stream>>>(rel_w0, root_w0, rel_w1, root_w1, Wt);
    cast_x<<<nb_cast, 256, 0, stream>>>(x, xc, N * FDIM, NPAD * FDIM);

    seg_mean<<<nb_mean, 256, 0, stream>>>((const int4v*)head, meta, cnt, xc, Mm, NSEG);
    rgcn_gemm<false><<<nb_gemm, 512, 0, stream>>>(Mm, xc, Wt, bias0, nullptr, h1c, N);
    seg_mean<<<nb_mean, 256, 0, stream>>>((const int4v*)head, meta, cnt, h1c, Mm, NSEG);
    rgcn_gemm<true><<<nb_gemm, 512, 0, stream>>>(Mm, h1c, Wt + 9 * 16384, bias1,
                                                 (float*)d_out, nullptr, N);
    copy_emb<<<4, 256, 0, stream>>>(rel_emb, (float*)d_out + (size_t)N * FDIM,
                                    in_sizes[9]);
}

// Round 10
// 341.902 us; speedup vs baseline: 1.0230x; 1.0230x over previous
//
#include <hip/hip_runtime.h>

typedef unsigned short ushort_t;
typedef __attribute__((ext_vector_type(8))) short short8;
typedef __attribute__((ext_vector_type(4))) float f32x4;
typedef __attribute__((ext_vector_type(4))) int int4v;

#define RNUM 8
#define FDIM 128

__device__ __forceinline__ float bf2f(ushort_t u) {
    union { unsigned int i; float f; } x;
    x.i = ((unsigned int)u) << 16;
    return x.f;
}
__device__ __forceinline__ ushort_t f2bf(float f) {
    union { float f; unsigned int i; } x;
    x.f = f;
    unsigned int u = x.i;
    u += 0x7fffu + ((u >> 16) & 1u);   // round-to-nearest-even
    return (ushort_t)(u >> 16);
}

// ---------------- multi-head linked-list segment index ----------------
// Round-7 form (measured best): 4 sub-lists per segment keyed by edge_id&3,
// ONE independent atomicExch per edge (round-9's atomicAdd+atomicExch
// dependent chain was latency-serialized: 65us, VALUBusy 0.5%).
// meta[i] = (src[i], prev edge in same (seg,k) list). One 8B load per hop.

__global__ void link_kernel(const int* __restrict__ src, const int* __restrict__ dst,
                            const int* __restrict__ et,
                            int* head, int2* __restrict__ meta, int E) {
    int i = blockIdx.x * 256 + threadIdx.x;
    if (i < E) {
        int seg = dst[i] * RNUM + et[i];
        int prev = atomicExch(&head[seg * 4 + (i & 3)], i);
        meta[i] = make_int2(src[i], prev);
    }
}

// ---------------- fused prologue: independent prep jobs in ONE launch --------------
// blocks 0..17: weight transpose+cast  Wt[l][r][h][f] = bf16(W_l[r][f][h])
// block  18   : copy rel_emb tail of the output
// blocks 19..19+nbHead-1: head[] = -1
// rest        : cast x (f32) -> compact bf16 xc (pad rows zeroed)
// On one stream these previously serialized (sum); fused they run
// concurrently (max). Saves ~5-8us of prologue wall time.

__global__ __launch_bounds__(256) void prologue_fused(
    const float* __restrict__ rel_w0, const float* __restrict__ root_w0,
    const float* __restrict__ rel_w1, const float* __restrict__ root_w1,
    ushort_t* __restrict__ Wt,
    const float* __restrict__ x, ushort_t* __restrict__ xc,
    int total, int totalPad,
    int* __restrict__ head, int nhead,
    const float* __restrict__ emb, float* __restrict__ outEmb, int nemb,
    int nbHead) {
    __shared__ ushort_t t[128 * 130];
    int b = blockIdx.x, tid = threadIdx.x;
    if (b < 18) {
        int layer = (b >= 9) ? 1 : 0;
        int r = b - layer * 9;         // 0..8, r=8 -> root
        const float* rel  = layer ? rel_w1 : rel_w0;
        const float* root = layer ? root_w1 : root_w0;
        const float* src = (r < 8) ? (rel + r * 16384) : root;
        for (int idx = tid; idx < 16384; idx += 256)
            t[(idx >> 7) * 130 + (idx & 127)] = f2bf(src[idx]);
        __syncthreads();
        ushort_t* d = Wt + (layer * 9 + r) * 16384;
        for (int idx = tid; idx < 16384; idx += 256)
            d[idx] = t[(idx & 127) * 130 + (idx >> 7)];
    } else if (b == 18) {
        for (int i = tid; i < nemb; i += 256) outEmb[i] = emb[i];
    } else if (b < 19 + nbHead) {
        int i = (b - 19) * 256 + tid;
        if (i < nhead) head[i] = -1;
    } else {
        int i = ((b - 19 - nbHead) * 256 + tid) * 8;
        if (i < totalPad) {
            ushort_t o[8];
            if (i < total) {
                float4 v0 = *(const float4*)(x + i);
                float4 v1 = *(const float4*)(x + i + 4);
                o[0] = f2bf(v0.x); o[1] = f2bf(v0.y); o[2] = f2bf(v0.z); o[3] = f2bf(v0.w);
                o[4] = f2bf(v1.x); o[5] = f2bf(v1.y); o[6] = f2bf(v1.z); o[7] = f2bf(v1.w);
            } else {
#pragma unroll
                for (int k = 0; k < 8; ++k) o[k] = 0;
            }
            *(int4v*)(xc + i) = *(int4v*)o;
        }
    }
}

// ---------------- phase A: per-(node,rel) segment means ----------------
// ROUND-7 VERSION VERBATIM (measured 61.7us; at the random-gather pattern
// roofline ~3.8-4.1 TB/s across VALUBusy 31-64% configs -- do not touch).
// One quarter-wave (16 lanes x 16B) per segment; the segment's 4 sub-chains
// walked interleaved (4 independent gathers in flight). Exec-masked guards:
// dead chains issue no loads. All addresses pow2 shifts. Cached stores
// (Mm stays L2/L3-resident for the GEMM that reads it next).

__global__ __launch_bounds__(256) void seg_mean(const int4v* __restrict__ head4,
                                                const int2* __restrict__ meta,
                                                const ushort_t* __restrict__ X,   // [NPAD][128]
                                                ushort_t* __restrict__ Mm,        // [NPAD][8][128]
                                                int NSEG) {
    int t = blockIdx.x * 256 + threadIdx.x;
    int seg = t >> 4;
    int l16 = t & 15;
    if (seg >= NSEG) return;
    const ushort_t* gbase = X + l16 * 8;

    float acc[8];
#pragma unroll
    for (int k = 0; k < 8; ++k) acc[k] = 0.f;

    int4v h4 = head4[seg];           // 4 sub-chain heads in one 16B load
    int j[4], s[4], n[4];
#pragma unroll
    for (int c = 0; c < 4; ++c) j[c] = h4[c];
#pragma unroll
    for (int c = 0; c < 4; ++c)
        if (j[c] >= 0) { int2 m = meta[j[c]]; s[c] = m.x; n[c] = m.y; }

    int cnt = 0;
    // loop while ANY sub-chain active (AND of ids has sign bit set iff all -1)
    while ((j[0] & j[1] & j[2] & j[3]) >= 0) {
        int4v v[4];
#pragma unroll
        for (int c = 0; c < 4; ++c)
            if (j[c] >= 0) v[c] = *(const int4v*)(gbase + ((size_t)s[c] << 7));
        int2 m2[4];
#pragma unroll
        for (int c = 0; c < 4; ++c)
            if (j[c] >= 0 && n[c] >= 0) m2[c] = meta[n[c]];
#pragma unroll
        for (int c = 0; c < 4; ++c) {
            if (j[c] >= 0) {
                const ushort_t* p = (const ushort_t*)&v[c];
#pragma unroll
                for (int k = 0; k < 8; ++k) acc[k] += bf2f(p[k]);
                ++cnt;
                j[c] = n[c];
                s[c] = m2[c].x;
                n[c] = m2[c].y;
            }
        }
    }

    float sc = (cnt > 0) ? 1.0f / (float)cnt : 0.f;
    ushort_t ov[8];
#pragma unroll
    for (int k = 0; k < 8; ++k) ov[k] = f2bf(acc[k] * sc);
    *(int4v*)(Mm + ((size_t)seg << 7) + l16 * 8) = *(int4v*)ov;
}

// ---------------- phase B: dense GEMM  C[128n x 128h] = [Mm | Xc] @ Wt^T ----------------
// Register-staged K-slot pipeline, 512 threads / 8 waves (16 waves/CU at
// 2 blocks/CU). NEW vs round 7: A-loads are TWO slots deep (two alternating
// reg sets; slot r+2's A issued before slot r's compute) so the vmcnt wait in
// writeLds sits ~1200cy after issue -- covers the ~900cy HBM/L3 latency that
// a single compute phase (~600cy) did not. B stays 1-deep: the 144KB weight
// tensor is L2-resident after the first blocks (hit ~200cy).

template <bool FINAL>
__global__ __launch_bounds__(512, 4) void rgcn_gemm(
    const ushort_t* __restrict__ Mm,   // [NPAD][8*128]
    const ushort_t* __restrict__ Xc,   // [NPAD][128]  (slot 8 / root input)
    const ushort_t* __restrict__ Wt,   // [9][128][128]
    const float* __restrict__ bias, float* __restrict__ outF,
    ushort_t* __restrict__ Xout, int N) {
    __shared__ ushort_t As[128 * 128];
    __shared__ ushort_t Bs[128 * 128];
    int tid = threadIdx.x;
    int wv = tid >> 6, lane = tid & 63;
    int l16 = lane & 15, q = lane >> 4;
    int nodeBase = blockIdx.x * 128;

    f32x4 acc[8];
#pragma unroll
    for (int ct = 0; ct < 8; ++ct) acc[ct] = (f32x4){0.f, 0.f, 0.f, 0.f};

    int4v aR0[4], aR1[4], bR[4];

    auto loadA = [&](int4v* dstReg, int r) {
#pragma unroll
        for (int i = 0; i < 4; ++i) {
            int L = i * 512 + tid;          // 16B slot index, wave-contiguous
            int row = L >> 4;               // 0..127
            int c = (L & 15) ^ (row & 15);  // logical chunk for this slot (swizzle)
            const ushort_t* ga = (r < 8)
                ? Mm + ((size_t)(nodeBase + row) << 10) + r * 128 + c * 8
                : Xc + ((size_t)(nodeBase + row) << 7) + c * 8;
            dstReg[i] = *(const int4v*)ga;
        }
    };
    auto loadB = [&](int r) {
#pragma unroll
        for (int i = 0; i < 4; ++i) {
            int L = i * 512 + tid;
            int row = L >> 4;
            int c = (L & 15) ^ (row & 15);
            bR[i] = *(const int4v*)(Wt + r * 16384 + row * 128 + c * 8);
        }
    };
    auto writeLds = [&](int4v* aReg) {
#pragma unroll
        for (int i = 0; i < 4; ++i) {
            int L = i * 512 + tid;
            *(int4v*)((char*)As + (size_t)L * 16) = aReg[i];
            *(int4v*)((char*)Bs + (size_t)L * 16) = bR[i];
        }
    };

    // prologue: slot0 -> aR0 (+B), slot1 -> aR1 in flight; stage slot0
    loadA(aR0, 0);
    loadB(0);
    loadA(aR1, 1);
    writeLds(aR0);            // waits vmcnt on aR0/bR only; aR1 stays outstanding
    __syncthreads();

    for (int r = 0; r < 9; ++r) {
        // slot r in LDS, slot r+1 in aR[(r+1)&1]; free set aR[r&1] takes r+2
        if (r < 7) loadA((r & 1) ? aR1 : aR0, r + 2);
        if (r < 8) loadB(r + 1);            // L2-hit; one-phase cover suffices
#pragma unroll
        for (int s = 0; s < 4; ++s) {
            int pos = ((s * 4 + q) ^ l16) * 16;
            short8 a = *(const short8*)((const char*)As + (wv * 16 + l16) * 256 + pos);
#pragma unroll
            for (int ct = 0; ct < 8; ++ct) {
                short8 b = *(const short8*)((const char*)Bs + (ct * 16 + l16) * 256 + pos);
                acc[ct] = __builtin_amdgcn_mfma_f32_16x16x32_bf16(a, b, acc[ct], 0, 0, 0);
            }
        }
        __syncthreads();                     // all LDS reads of slot r done
        if (r < 8) {
            writeLds(((r + 1) & 1) ? aR1 : aR0);  // waits slot r+1 (issued 2 phases ago)
            __syncthreads();                 // writes visible before next compute
        }
    }

    // epilogue: C layout col = lane&15, row = q*4 + reg (within wave's 16-row tile)
#pragma unroll
    for (int ct = 0; ct < 8; ++ct) {
        int h = ct * 16 + l16;
        float bv = bias[h];
#pragma unroll
        for (int reg = 0; reg < 4; ++reg) {
            int node = nodeBase + wv * 16 + q * 4 + reg;
            float v = acc[ct][reg] + bv;
            if (FINAL) {
                if (node < N) outF[(size_t)node * FDIM + h] = v;
            } else {
                // pad rows written as 0 (keeps h1c defined; acc there is garbage)
                Xout[(size_t)node * FDIM + h] =
                    (node < N) ? f2bf(fmaxf(v, 0.f)) : (ushort_t)0;
            }
        }
    }
}

// ---------------- launch ----------------

extern "C" void kernel_launch(void* const* d_in, const int* in_sizes, int n_in,
                              void* d_out, int out_size, void* d_ws, size_t ws_size,
                              hipStream_t stream) {
    const float* x        = (const float*)d_in[0];
    const int* edge_index = (const int*)d_in[1];
    const int* edge_type  = (const int*)d_in[2];
    const float* rel_w0   = (const float*)d_in[3];
    const float* root_w0  = (const float*)d_in[4];
    const float* bias0    = (const float*)d_in[5];
    const float* rel_w1   = (const float*)d_in[6];
    const float* root_w1  = (const float*)d_in[7];
    const float* bias1    = (const float*)d_in[8];
    const float* rel_emb  = (const float*)d_in[9];

    int N = in_sizes[0] / FDIM;   // 50000
    int E = in_sizes[1] / 2;      // 800000
    int NSEG = N * RNUM;          // 400000
    const int* src = edge_index;
    const int* dst = edge_index + E;

    int nb_gemm = (N + 127) / 128;      // 391
    int NPAD = nb_gemm * 128;           // 50048

    char* w = (char*)d_ws;
    auto alloc = [&](size_t bytes) -> char* {
        char* p = w;
        w += (bytes + 255) & ~(size_t)255;
        return p;
    };
    int* head     = (int*)alloc((size_t)NSEG * 4 * 4);          // 4 sub-lists per segment
    int2* meta    = (int2*)alloc((size_t)E * 8);
    ushort_t* Wt  = (ushort_t*)alloc((size_t)2 * 9 * 16384 * 2);
    ushort_t* xc  = (ushort_t*)alloc((size_t)NPAD * FDIM * 2);        // 12.8 MB
    ushort_t* h1c = (ushort_t*)alloc((size_t)NPAD * FDIM * 2);        // 12.8 MB
    ushort_t* Mm  = (ushort_t*)alloc((size_t)NPAD * RNUM * FDIM * 2); // ~102.5 MB
    (void)ws_size; (void)n_in; (void)out_size;

    int nhead   = NSEG * 4;
    int nb_head = (nhead + 255) / 256;
    int nb_E    = (E + 255) / 256;
    int nb_mean = (NSEG * 16) / 256;                 // 25000
    int nb_cast = (NPAD * FDIM) / (256 * 8);         // 3128
    int nb_pro  = 19 + nb_head + nb_cast;

    prologue_fused<<<nb_pro, 256, 0, stream>>>(
        rel_w0, root_w0, rel_w1, root_w1, Wt,
        x, xc, N * FDIM, NPAD * FDIM,
        head, nhead,
        rel_emb, (float*)d_out + (size_t)N * FDIM, in_sizes[9],
        nb_head);
    link_kernel<<<nb_E, 256, 0, stream>>>(src, dst, edge_type, head, meta, E);

    seg_mean<<<nb_mean, 256, 0, stream>>>((const int4v*)head, meta, xc, Mm, NSEG);
    rgcn_gemm<false><<<nb_gemm, 512, 0, stream>>>(Mm, xc, Wt, bias0, nullptr, h1c, N);
    seg_mean<<<nb_mean, 256, 0, stream>>>((const int4v*)head, meta, h1c, Mm, NSEG);
    rgcn_gemm<true><<<nb_gemm, 512, 0, stream>>>(Mm, h1c, Wt + 9 * 16384, bias1,
                                                 (float*)d_out, nullptr, N);
}

// Round 11
// 303.813 us; speedup vs baseline: 1.1512x; 1.1254x over previous
//
#include <hip/hip_runtime.h>

typedef unsigned short ushort_t;
typedef __attribute__((ext_vector_type(8))) short short8;
typedef __attribute__((ext_vector_type(4))) float f32x4;
typedef __attribute__((ext_vector_type(4))) int int4v;

#define RNUM 8
#define FDIM 128

__device__ __forceinline__ float bf2f(ushort_t u) {
    union { unsigned int i; float f; } x;
    x.i = ((unsigned int)u) << 16;
    return x.f;
}
__device__ __forceinline__ ushort_t f2bf(float f) {
    union { float f; unsigned int i; } x;
    x.f = f;
    unsigned int u = x.i;
    u += 0x7fffu + ((u >> 16) & 1u);   // round-to-nearest-even
    return (ushort_t)(u >> 16);
}

// ---------------- multi-head linked-list segment index ----------------
// Round-7 form (measured best): 4 sub-lists per segment keyed by edge_id&3,
// ONE independent atomicExch per edge (round-9's atomicAdd+atomicExch
// dependent chain was latency-serialized: 65us, VALUBusy 0.5%).
// meta[i] = (src[i], prev edge in same (seg,k) list). One 8B load per hop.

__global__ void link_kernel(const int* __restrict__ src, const int* __restrict__ dst,
                            const int* __restrict__ et,
                            int* head, int2* __restrict__ meta, int E) {
    int i = blockIdx.x * 256 + threadIdx.x;
    if (i < E) {
        int seg = dst[i] * RNUM + et[i];
        int prev = atomicExch(&head[seg * 4 + (i & 3)], i);
        meta[i] = make_int2(src[i], prev);
    }
}

// ---------------- fused prologue: independent prep jobs in ONE launch --------------
// blocks 0..17: weight transpose+cast  Wt[l][r][h][f] = bf16(W_l[r][f][h])
// block  18   : copy rel_emb tail of the output
// blocks 19..19+nbHead-1: head[] = -1
// rest        : cast x (f32) -> compact bf16 xc (pad rows zeroed)

__global__ __launch_bounds__(256) void prologue_fused(
    const float* __restrict__ rel_w0, const float* __restrict__ root_w0,
    const float* __restrict__ rel_w1, const float* __restrict__ root_w1,
    ushort_t* __restrict__ Wt,
    const float* __restrict__ x, ushort_t* __restrict__ xc,
    int total, int totalPad,
    int* __restrict__ head, int nhead,
    const float* __restrict__ emb, float* __restrict__ outEmb, int nemb,
    int nbHead) {
    __shared__ ushort_t t[128 * 130];
    int b = blockIdx.x, tid = threadIdx.x;
    if (b < 18) {
        int layer = (b >= 9) ? 1 : 0;
        int r = b - layer * 9;         // 0..8, r=8 -> root
        const float* rel  = layer ? rel_w1 : rel_w0;
        const float* root = layer ? root_w1 : root_w0;
        const float* src = (r < 8) ? (rel + r * 16384) : root;
        for (int idx = tid; idx < 16384; idx += 256)
            t[(idx >> 7) * 130 + (idx & 127)] = f2bf(src[idx]);
        __syncthreads();
        ushort_t* d = Wt + (layer * 9 + r) * 16384;
        for (int idx = tid; idx < 16384; idx += 256)
            d[idx] = t[(idx & 127) * 130 + (idx >> 7)];
    } else if (b == 18) {
        for (int i = tid; i < nemb; i += 256) outEmb[i] = emb[i];
    } else if (b < 19 + nbHead) {
        int i = (b - 19) * 256 + tid;
        if (i < nhead) head[i] = -1;
    } else {
        int i = ((b - 19 - nbHead) * 256 + tid) * 8;
        if (i < totalPad) {
            ushort_t o[8];
            if (i < total) {
                float4 v0 = *(const float4*)(x + i);
                float4 v1 = *(const float4*)(x + i + 4);
                o[0] = f2bf(v0.x); o[1] = f2bf(v0.y); o[2] = f2bf(v0.z); o[3] = f2bf(v0.w);
                o[4] = f2bf(v1.x); o[5] = f2bf(v1.y); o[6] = f2bf(v1.z); o[7] = f2bf(v1.w);
            } else {
#pragma unroll
                for (int k = 0; k < 8; ++k) o[k] = 0;
            }
            *(int4v*)(xc + i) = *(int4v*)o;
        }
    }
}

// ---------------- phase A: per-(node,rel) segment means ----------------
// ROUND-7 VERSION VERBATIM (measured 61.2-61.7us; at the random-gather
// pattern roofline ~3.8-4.1 TB/s across VALUBusy 31-64% configs; round-9's
// VALU-cut falsification proved duration is pinned by gather service rate).
// One quarter-wave (16 lanes x 16B) per segment; the segment's 4 sub-chains
// walked interleaved (4 independent gathers in flight). Exec-masked guards:
// dead chains issue no loads. All addresses pow2 shifts. Cached stores
// (Mm stays L2/L3-resident for the GEMM that reads it next).

__global__ __launch_bounds__(256) void seg_mean(const int4v* __restrict__ head4,
                                                const int2* __restrict__ meta,
                                                const ushort_t* __restrict__ X,   // [NPAD][128]
                                                ushort_t* __restrict__ Mm,        // [NPAD][8][128]
                                                int NSEG) {
    int t = blockIdx.x * 256 + threadIdx.x;
    int seg = t >> 4;
    int l16 = t & 15;
    if (seg >= NSEG) return;
    const ushort_t* gbase = X + l16 * 8;

    float acc[8];
#pragma unroll
    for (int k = 0; k < 8; ++k) acc[k] = 0.f;

    int4v h4 = head4[seg];           // 4 sub-chain heads in one 16B load
    int j[4], s[4], n[4];
#pragma unroll
    for (int c = 0; c < 4; ++c) j[c] = h4[c];
#pragma unroll
    for (int c = 0; c < 4; ++c)
        if (j[c] >= 0) { int2 m = meta[j[c]]; s[c] = m.x; n[c] = m.y; }

    int cnt = 0;
    // loop while ANY sub-chain active (AND of ids has sign bit set iff all -1)
    while ((j[0] & j[1] & j[2] & j[3]) >= 0) {
        int4v v[4];
#pragma unroll
        for (int c = 0; c < 4; ++c)
            if (j[c] >= 0) v[c] = *(const int4v*)(gbase + ((size_t)s[c] << 7));
        int2 m2[4];
#pragma unroll
        for (int c = 0; c < 4; ++c)
            if (j[c] >= 0 && n[c] >= 0) m2[c] = meta[n[c]];
#pragma unroll
        for (int c = 0; c < 4; ++c) {
            if (j[c] >= 0) {
                const ushort_t* p = (const ushort_t*)&v[c];
#pragma unroll
                for (int k = 0; k < 8; ++k) acc[k] += bf2f(p[k]);
                ++cnt;
                j[c] = n[c];
                s[c] = m2[c].x;
                n[c] = m2[c].y;
            }
        }
    }

    float sc = (cnt > 0) ? 1.0f / (float)cnt : 0.f;
    ushort_t ov[8];
#pragma unroll
    for (int k = 0; k < 8; ++k) ov[k] = f2bf(acc[k] * sc);
    *(int4v*)(Mm + ((size_t)seg << 7) + l16 * 8) = *(int4v*)ov;
}

// ---------------- phase B: dense GEMM  C[128n x 128h] = [Mm | Xc] @ Wt^T ----------------
// ROUND-7 VERSION VERBATIM (total was 315.2us with it). 1-deep register-
// staged K-slot pipeline, 512 threads / 8 waves (16 waves/CU at 2 blocks/CU).
// Round-10's 2-deep A pipeline was structurally broken: vmcnt is in-order,
// so waiting on the (newer) B regs in writeLds drained the prefetched A(r+2)
// loads anyway, while the 3rd reg set pushed allocation against the 128-VGPR
// cap (spill risk). Reverted.

template <bool FINAL>
__global__ __launch_bounds__(512, 4) void rgcn_gemm(
    const ushort_t* __restrict__ Mm,   // [NPAD][8*128]
    const ushort_t* __restrict__ Xc,   // [NPAD][128]  (slot 8 / root input)
    const ushort_t* __restrict__ Wt,   // [9][128][128]
    const float* __restrict__ bias, float* __restrict__ outF,
    ushort_t* __restrict__ Xout, int N) {
    __shared__ ushort_t As[128 * 128];
    __shared__ ushort_t Bs[128 * 128];
    int tid = threadIdx.x;
    int wv = tid >> 6, lane = tid & 63;
    int l16 = lane & 15, q = lane >> 4;
    int nodeBase = blockIdx.x * 128;

    f32x4 acc[8];
#pragma unroll
    for (int ct = 0; ct < 8; ++ct) acc[ct] = (f32x4){0.f, 0.f, 0.f, 0.f};

    int4v aReg[4], bReg[4];

    auto issueLoads = [&](int r) {
#pragma unroll
        for (int i = 0; i < 4; ++i) {
            int L = i * 512 + tid;          // 16B slot index, wave-contiguous
            int row = L >> 4;               // 0..127
            int c = (L & 15) ^ (row & 15);  // logical chunk for this slot (swizzle)
            const ushort_t* ga = (r < 8)
                ? Mm + ((size_t)(nodeBase + row) << 10) + r * 128 + c * 8
                : Xc + ((size_t)(nodeBase + row) << 7) + c * 8;
            aReg[i] = *(const int4v*)ga;
            bReg[i] = *(const int4v*)(Wt + r * 16384 + row * 128 + c * 8);
        }
    };
    auto writeLds = [&]() {
#pragma unroll
        for (int i = 0; i < 4; ++i) {
            int L = i * 512 + tid;
            *(int4v*)((char*)As + (size_t)L * 16) = aReg[i];
            *(int4v*)((char*)Bs + (size_t)L * 16) = bReg[i];
        }
    };

    issueLoads(0);
    writeLds();
    __syncthreads();

    for (int r = 0; r < 9; ++r) {
        if (r < 8) issueLoads(r + 1);       // in flight across the compute phase
#pragma unroll
        for (int s = 0; s < 4; ++s) {
            int pos = ((s * 4 + q) ^ l16) * 16;
            short8 a = *(const short8*)((const char*)As + (wv * 16 + l16) * 256 + pos);
#pragma unroll
            for (int ct = 0; ct < 8; ++ct) {
                short8 b = *(const short8*)((const char*)Bs + (ct * 16 + l16) * 256 + pos);
                acc[ct] = __builtin_amdgcn_mfma_f32_16x16x32_bf16(a, b, acc[ct], 0, 0, 0);
            }
        }
        __syncthreads();                     // all LDS reads of slot r done
        if (r < 8) {
            writeLds();                      // waits vmcnt on the staged regs only
            __syncthreads();                 // writes visible before next compute
        }
    }

    // epilogue: C layout col = lane&15, row = q*4 + reg (within wave's 16-row tile)
#pragma unroll
    for (int ct = 0; ct < 8; ++ct) {
        int h = ct * 16 + l16;
        float bv = bias[h];
#pragma unroll
        for (int reg = 0; reg < 4; ++reg) {
            int node = nodeBase + wv * 16 + q * 4 + reg;
            float v = acc[ct][reg] + bv;
            if (FINAL) {
                if (node < N) outF[(size_t)node * FDIM + h] = v;
            } else {
                // pad rows written as 0 (keeps h1c defined; acc there is garbage)
                Xout[(size_t)node * FDIM + h] =
                    (node < N) ? f2bf(fmaxf(v, 0.f)) : (ushort_t)0;
            }
        }
    }
}

// ---------------- launch ----------------

extern "C" void kernel_launch(void* const* d_in, const int* in_sizes, int n_in,
                              void* d_out, int out_size, void* d_ws, size_t ws_size,
                              hipStream_t stream) {
    const float* x        = (const float*)d_in[0];
    const int* edge_index = (const int*)d_in[1];
    const int* edge_type  = (const int*)d_in[2];
    const float* rel_w0   = (const float*)d_in[3];
    const float* root_w0  = (const float*)d_in[4];
    const float* bias0    = (const float*)d_in[5];
    const float* rel_w1   = (const float*)d_in[6];
    const float* root_w1  = (const float*)d_in[7];
    const float* bias1    = (const float*)d_in[8];
    const float* rel_emb  = (const float*)d_in[9];

    int N = in_sizes[0] / FDIM;   // 50000
    int E = in_sizes[1] / 2;      // 800000
    int NSEG = N * RNUM;          // 400000
    const int* src = edge_index;
    const int* dst = edge_index + E;

    int nb_gemm = (N + 127) / 128;      // 391
    int NPAD = nb_gemm * 128;           // 50048

    char* w = (char*)d_ws;
    auto alloc = [&](size_t bytes) -> char* {
        char* p = w;
        w += (bytes + 255) & ~(size_t)255;
        return p;
    };
    int* head     = (int*)alloc((size_t)NSEG * 4 * 4);          // 4 sub-lists per segment
    int2* meta    = (int2*)alloc((size_t)E * 8);
    ushort_t* Wt  = (ushort_t*)alloc((size_t)2 * 9 * 16384 * 2);
    ushort_t* xc  = (ushort_t*)alloc((size_t)NPAD * FDIM * 2);        // 12.8 MB
    ushort_t* h1c = (ushort_t*)alloc((size_t)NPAD * FDIM * 2);        // 12.8 MB
    ushort_t* Mm  = (ushort_t*)alloc((size_t)NPAD * RNUM * FDIM * 2); // ~102.5 MB
    (void)ws_size; (void)n_in; (void)out_size;

    int nhead   = NSEG * 4;
    int nb_head = (nhead + 255) / 256;
    int nb_E    = (E + 255) / 256;
    int nb_mean = (NSEG * 16) / 256;                 // 25000
    int nb_cast = (NPAD * FDIM) / (256 * 8);         // 3128
    int nb_pro  = 19 + nb_head + nb_cast;

    prologue_fused<<<nb_pro, 256, 0, stream>>>(
        rel_w0, root_w0, rel_w1, root_w1, Wt,
        x, xc, N * FDIM, NPAD * FDIM,
        head, nhead,
        rel_emb, (float*)d_out + (size_t)N * FDIM, in_sizes[9],
        nb_head);
    link_kernel<<<nb_E, 256, 0, stream>>>(src, dst, edge_type, head, meta, E);

    seg_mean<<<nb_mean, 256, 0, stream>>>((const int4v*)head, meta, xc, Mm, NSEG);
    rgcn_gemm<false><<<nb_gemm, 512, 0, stream>>>(Mm, xc, Wt, bias0, nullptr, h1c, N);
    seg_mean<<<nb_mean, 256, 0, stream>>>((const int4v*)head, meta, h1c, Mm, NSEG);
    rgcn_gemm<true><<<nb_gemm, 512, 0, stream>>>(Mm, h1c, Wt + 9 * 16384, bias1,
                                                 (float*)d_out, nullptr, N);
}